// Round 5
// baseline (452.738 us; speedup 1.0000x reference)
//
#include <hip/hip_runtime.h>

#define IN_DIM 128
#define HID 64
#define ODIM 40

// ================= degree =================

__global__ __launch_bounds__(256) void k_count(const int* __restrict__ dst,
                                               int* __restrict__ deg, int e) {
    int i = blockIdx.x * 256 + threadIdx.x;
    if (i < e) atomicAdd(&deg[dst[i]], 1);
}

// ================= exclusive scan (rowptr) + dinv =================
// chunk = 1024 elements per block (256 thr x 4)

__global__ __launch_bounds__(256) void k_chunksum(const int* __restrict__ deg,
                                                  int* __restrict__ csum, int n) {
    __shared__ int red[256];
    const int tid = threadIdx.x;
    int base = blockIdx.x * 1024 + tid * 4;
    int s = 0;
#pragma unroll
    for (int j = 0; j < 4; ++j) {
        int idx = base + j;
        if (idx < n) s += deg[idx];
    }
    red[tid] = s;
    __syncthreads();
    for (int off = 128; off > 0; off >>= 1) {
        if (tid < off) red[tid] += red[tid + off];
        __syncthreads();
    }
    if (tid == 0) csum[blockIdx.x] = red[0];
}

// single block: exclusive scan of csum[nchunks] (nchunks <= 256); also rowptr[n] = e
__global__ __launch_bounds__(256) void k_scanchunks(int* __restrict__ csum, int nchunks,
                                                    int* __restrict__ rowptr, int n, int e) {
    __shared__ int tmp[256];
    const int tid = threadIdx.x;
    int v = (tid < nchunks) ? csum[tid] : 0;
    tmp[tid] = v;
    __syncthreads();
    for (int off = 1; off < 256; off <<= 1) {
        int t = (tid >= off) ? tmp[tid - off] : 0;
        __syncthreads();
        tmp[tid] += t;
        __syncthreads();
    }
    if (tid < nchunks) csum[tid] = tmp[tid] - v;  // exclusive
    if (tid == 0) rowptr[n] = e;
}

// rowptr write + dinv fused (both read deg)
__global__ __launch_bounds__(256) void k_scanwrite(const int* __restrict__ deg,
                                                   const int* __restrict__ csum,
                                                   int* __restrict__ rowptr,
                                                   float* __restrict__ dinv, int n) {
    __shared__ int tsum[256];
    const int tid = threadIdx.x;
    int base = blockIdx.x * 1024 + tid * 4;
    int v[4];
#pragma unroll
    for (int j = 0; j < 4; ++j) {
        int idx = base + j;
        v[j] = (idx < n) ? deg[idx] : 0;
    }
    int pre1 = v[0], pre2 = v[0] + v[1], pre3 = pre2 + v[2];
    int tot = pre3 + v[3];
    tsum[tid] = tot;
    __syncthreads();
    for (int off = 1; off < 256; off <<= 1) {
        int t = (tid >= off) ? tsum[tid - off] : 0;
        __syncthreads();
        tsum[tid] += t;
        __syncthreads();
    }
    int excl = tsum[tid] - tot;
    int off0 = csum[blockIdx.x] + excl;
    int pre[4] = {0, pre1, pre2, pre3};
#pragma unroll
    for (int j = 0; j < 4; ++j) {
        int idx = base + j;
        if (idx < n) {
            rowptr[idx] = off0 + pre[j];
            dinv[idx] = rsqrtf((float)(v[j] + 1));  // +1 self loop; always > 0
        }
    }
}

// fill: place src of each edge into its dst bucket
__global__ __launch_bounds__(256) void k_fill(const int* __restrict__ src,
                                              const int* __restrict__ dst,
                                              const int* __restrict__ rowptr,
                                              int* __restrict__ cursor,
                                              int* __restrict__ esrc, int e) {
    int i = blockIdx.x * 256 + threadIdx.x;
    if (i < e) {
        int d = dst[i];
        int p = rowptr[d] + atomicAdd(&cursor[d], 1);
        esrc[p] = src[i];
    }
}

// ================= GEMM1: P1 = (x @ W1) * dinv[row]  [N,128]x[128,64] =================

__global__ __launch_bounds__(256) void k_gemm1(const float* __restrict__ x,
                                               const float* __restrict__ W,
                                               const float* __restrict__ dinv,
                                               float* __restrict__ P, int n) {
    __shared__ float Ws[IN_DIM * HID];  // 32 KB
    const int t = threadIdx.x;
    {
        const float4* W4 = (const float4*)W;
        float4* Ws4 = (float4*)Ws;
#pragma unroll
        for (int i = 0; i < 8; ++i) Ws4[t + 256 * i] = W4[t + 256 * i];
    }
    __syncthreads();

    const int row0 = blockIdx.x * 64;
    const int ty = t >> 4, tx = t & 15;  // 4 rows x 4 cols per thread
    float acc[4][4];
#pragma unroll
    for (int i = 0; i < 4; ++i)
#pragma unroll
        for (int j = 0; j < 4; ++j) acc[i][j] = 0.f;

    const float4* x4 = (const float4*)x;
    int gr[4];
#pragma unroll
    for (int i = 0; i < 4; ++i) {
        int r = row0 + ty * 4 + i;
        gr[i] = r < n ? r : (n - 1);  // clamp for safe load; store is guarded
    }

#pragma unroll 2
    for (int k = 0; k < IN_DIM; k += 4) {
        float aa[4][4];
#pragma unroll
        for (int i = 0; i < 4; ++i) {
            float4 av = x4[(size_t)gr[i] * 32 + (k >> 2)];
            aa[i][0] = av.x; aa[i][1] = av.y; aa[i][2] = av.z; aa[i][3] = av.w;
        }
#pragma unroll
        for (int q = 0; q < 4; ++q) {
            float4 bv = *(const float4*)&Ws[(k + q) * HID + tx * 4];
#pragma unroll
            for (int i = 0; i < 4; ++i) {
                acc[i][0] = fmaf(aa[i][q], bv.x, acc[i][0]);
                acc[i][1] = fmaf(aa[i][q], bv.y, acc[i][1]);
                acc[i][2] = fmaf(aa[i][q], bv.z, acc[i][2]);
                acc[i][3] = fmaf(aa[i][q], bv.w, acc[i][3]);
            }
        }
    }

#pragma unroll
    for (int i = 0; i < 4; ++i) {
        int r = row0 + ty * 4 + i;
        if (r < n) {
            float s = dinv[r];
            float4 o = make_float4(acc[i][0] * s, acc[i][1] * s, acc[i][2] * s, acc[i][3] * s);
            *(float4*)&P[(size_t)r * HID + tx * 4] = o;
        }
    }
}

// ================= GEMM2: P2 = (h @ W2) * dinv[row]  [N,64]x[64,40] =================

__global__ __launch_bounds__(256) void k_gemm2(const float* __restrict__ h,
                                               const float* __restrict__ W,
                                               const float* __restrict__ dinv,
                                               float* __restrict__ P, int n) {
    __shared__ float Ws[HID * 48];  // padded cols, 12 KB
    const int t = threadIdx.x;
#pragma unroll
    for (int i = 0; i < 12; ++i) {
        int idx = t + 256 * i;
        int r = idx / 48, c = idx - r * 48;
        Ws[idx] = (c < ODIM) ? W[r * ODIM + c] : 0.f;
    }
    __syncthreads();

    const int row0 = blockIdx.x * 64;
    const int ty = t >> 4, tx = t & 15;  // 4 rows x 3 cols
    float acc[4][3];
#pragma unroll
    for (int i = 0; i < 4; ++i)
#pragma unroll
        for (int j = 0; j < 3; ++j) acc[i][j] = 0.f;

    const float4* h4 = (const float4*)h;
    int gr[4];
#pragma unroll
    for (int i = 0; i < 4; ++i) {
        int r = row0 + ty * 4 + i;
        gr[i] = r < n ? r : (n - 1);
    }

#pragma unroll 2
    for (int k = 0; k < HID; k += 4) {
        float aa[4][4];
#pragma unroll
        for (int i = 0; i < 4; ++i) {
            float4 av = h4[(size_t)gr[i] * 16 + (k >> 2)];
            aa[i][0] = av.x; aa[i][1] = av.y; aa[i][2] = av.z; aa[i][3] = av.w;
        }
#pragma unroll
        for (int q = 0; q < 4; ++q) {
            const float* wr = &Ws[(k + q) * 48 + tx * 3];
            float b0 = wr[0], b1v = wr[1], b2v = wr[2];
#pragma unroll
            for (int i = 0; i < 4; ++i) {
                acc[i][0] = fmaf(aa[i][q], b0, acc[i][0]);
                acc[i][1] = fmaf(aa[i][q], b1v, acc[i][1]);
                acc[i][2] = fmaf(aa[i][q], b2v, acc[i][2]);
            }
        }
    }

#pragma unroll
    for (int i = 0; i < 4; ++i) {
        int r = row0 + ty * 4 + i;
        if (r < n) {
            float s = dinv[r];
#pragma unroll
            for (int j = 0; j < 3; ++j) {
                int c = tx * 3 + j;
                if (c < ODIM) P[(size_t)r * ODIM + c] = acc[i][j] * s;
            }
        }
    }
}

// ================= fused CSR aggregation + finalize =================
// layer1: one 64-lane wave per node. Lane l = (edge-slot grp = l>>4, float4-chunk q = l&15).
// Each iteration gathers 4 full P-rows (1 KB/wave); unroll 4 -> 16 gathers in flight.
// h[d] = relu(dinv[d] * (sum_{s in N(d)} P[s] + P[d]) + b)

__global__ __launch_bounds__(256) void k_agg1(const int* __restrict__ rowptr,
                                              const int* __restrict__ esrc,
                                              const float4* __restrict__ P4,
                                              const float* __restrict__ dinv,
                                              const float* __restrict__ b,
                                              float4* __restrict__ h4, int n) {
    const int t = threadIdx.x;
    const int lane = t & 63;
    const int node = blockIdx.x * 4 + (t >> 6);
    if (node >= n) return;
    const int grp = lane >> 4, q = lane & 15;  // 16 float4 = 64 feats
    const int beg = rowptr[node], end = rowptr[node + 1];

    float4 acc = make_float4(0.f, 0.f, 0.f, 0.f);
    int j = beg;
#pragma unroll 4
    for (; j + 3 < end; j += 4) {
        int s = esrc[j + grp];
        float4 v = P4[(size_t)s * 16 + q];
        acc.x += v.x; acc.y += v.y; acc.z += v.z; acc.w += v.w;
    }
    if (j + grp < end) {
        int s = esrc[j + grp];
        float4 v = P4[(size_t)s * 16 + q];
        acc.x += v.x; acc.y += v.y; acc.z += v.z; acc.w += v.w;
    }
    // combine the 4 edge-slots: xor 16 then xor 32
    acc.x += __shfl_xor(acc.x, 16); acc.y += __shfl_xor(acc.y, 16);
    acc.z += __shfl_xor(acc.z, 16); acc.w += __shfl_xor(acc.w, 16);
    acc.x += __shfl_xor(acc.x, 32); acc.y += __shfl_xor(acc.y, 32);
    acc.z += __shfl_xor(acc.z, 32); acc.w += __shfl_xor(acc.w, 32);

    if (grp == 0) {  // only the storing group touches self-row/dinv/bias
        float4 self = P4[(size_t)node * 16 + q];
        float di = dinv[node];
        float4 bb = *(const float4*)&b[q * 4];
        float4 r;
        r.x = fmaxf(fmaf(di, acc.x + self.x, bb.x), 0.f);
        r.y = fmaxf(fmaf(di, acc.y + self.y, bb.y), 0.f);
        r.z = fmaxf(fmaf(di, acc.z + self.z, bb.z), 0.f);
        r.w = fmaxf(fmaf(di, acc.w + self.w, bb.w), 0.f);
        h4[(size_t)node * 16 + q] = r;  // lanes 0-15: 256B store
    }
}

// layer2: 40 feats = 10 float4 per row (stride 160B, 16B aligned).
// 6 edge-slots x 10 chunks = 60 active lanes (grp = lane/10, q = lane%10).
// Per iteration: 6 P2-rows gathered (960B/wave), serial depth deg/6.
// 6-way combine: 3 shuffle steps (+30, +20, +10), result lands on lanes 0..9.

__global__ __launch_bounds__(256) void k_agg2(const int* __restrict__ rowptr,
                                              const int* __restrict__ esrc,
                                              const float4* __restrict__ P4,
                                              const float* __restrict__ dinv,
                                              const float* __restrict__ b,
                                              float4* __restrict__ out4, int n) {
    const int t = threadIdx.x;
    const int lane = t & 63;
    const int node = blockIdx.x * 4 + (t >> 6);
    if (node >= n) return;
    const int grp = lane / 10;          // 0..6 (lanes 60-63: grp 6, inactive)
    const int q = lane - grp * 10;      // 0..9
    const bool act = grp < 6;
    const int beg = rowptr[node], end = rowptr[node + 1];

    float4 acc = make_float4(0.f, 0.f, 0.f, 0.f);
    int j = beg;
#pragma unroll 4
    for (; j + 5 < end; j += 6) {
        if (act) {
            int s = esrc[j + grp];
            float4 v = P4[(size_t)s * 10 + q];
            acc.x += v.x; acc.y += v.y; acc.z += v.z; acc.w += v.w;
        }
    }
    if (act && j + grp < end) {
        int s = esrc[j + grp];
        float4 v = P4[(size_t)s * 10 + q];
        acc.x += v.x; acc.y += v.y; acc.z += v.z; acc.w += v.w;
    }

    // grp0 += grp3, grp1 += grp4, grp2 += grp5   (lanes < 30 read lane+30)
    {
        float tx_ = __shfl(acc.x, lane + 30), ty_ = __shfl(acc.y, lane + 30);
        float tz_ = __shfl(acc.z, lane + 30), tw_ = __shfl(acc.w, lane + 30);
        if (lane < 30) { acc.x += tx_; acc.y += ty_; acc.z += tz_; acc.w += tw_; }
    }
    // grp0 += grp2(+grp5)   (lanes < 10 read lane+20)
    {
        float tx_ = __shfl(acc.x, lane + 20), ty_ = __shfl(acc.y, lane + 20);
        float tz_ = __shfl(acc.z, lane + 20), tw_ = __shfl(acc.w, lane + 20);
        if (lane < 10) { acc.x += tx_; acc.y += ty_; acc.z += tz_; acc.w += tw_; }
    }
    // grp0 += grp1(+grp4)   (lanes < 10 read lane+10)
    {
        float tx_ = __shfl(acc.x, lane + 10), ty_ = __shfl(acc.y, lane + 10);
        float tz_ = __shfl(acc.z, lane + 10), tw_ = __shfl(acc.w, lane + 10);
        if (lane < 10) { acc.x += tx_; acc.y += ty_; acc.z += tz_; acc.w += tw_; }
    }

    if (lane < 10) {  // == (grp==0): full sums live here
        float4 self = P4[(size_t)node * 10 + q];
        float di = dinv[node];
        float4 bb = *(const float4*)&b[q * 4];
        float4 r;
        r.x = fmaf(di, acc.x + self.x, bb.x);
        r.y = fmaf(di, acc.y + self.y, bb.y);
        r.z = fmaf(di, acc.z + self.z, bb.z);
        r.w = fmaf(di, acc.w + self.w, bb.w);
        out4[(size_t)node * 10 + q] = r;  // 10 lanes: 160B store
    }
}

// ================= launch =================

extern "C" void kernel_launch(void* const* d_in, const int* in_sizes, int n_in,
                              void* d_out, int out_size, void* d_ws, size_t ws_size,
                              hipStream_t stream) {
    const float* x  = (const float*)d_in[0];
    const int*   ei = (const int*)d_in[1];
    const float* W1 = (const float*)d_in[2];
    const float* b1 = (const float*)d_in[3];
    const float* W2 = (const float*)d_in[4];
    const float* b2 = (const float*)d_in[5];

    const int n = in_sizes[0] / IN_DIM;   // 100000
    const int e = in_sizes[1] / 2;        // 1600000
    const int* src = ei;
    const int* dst = ei + e;
    const int nchunks = (n + 1023) >> 10; // 98 for n=100000

    auto align = [](size_t b) { return (b + 255) & ~(size_t)255; };
    char* ws = (char*)d_ws;
    size_t o = 0;
    int*   deg    = (int*)(ws + o);   o += (size_t)n * 4;   // deg+cursor adjacent: one memset
    int*   cursor = (int*)(ws + o);   o += (size_t)n * 4;
    o = align(o);
    float* dinv   = (float*)(ws + o); o += align((size_t)n * 4);
    int*   rowptr = (int*)(ws + o);   o += align((size_t)(n + 1) * 4);
    int*   csum   = (int*)(ws + o);   o += align((size_t)256 * 4);
    int*   esrc   = (int*)(ws + o);   o += align((size_t)e * 4);
    float* P1     = (float*)(ws + o); o += align((size_t)n * HID * 4);  // reused as P2
    float* h      = (float*)(ws + o); o += align((size_t)n * HID * 4);
    // total ~59 MB

    float* out = (float*)d_out;

    hipMemsetAsync(deg, 0, (size_t)n * 8, stream);  // deg + cursor

    // ---- CSR build (+dinv fused) ----
    k_count<<<(e + 255) / 256, 256, 0, stream>>>(dst, deg, e);
    k_chunksum<<<nchunks, 256, 0, stream>>>(deg, csum, n);
    k_scanchunks<<<1, 256, 0, stream>>>(csum, nchunks, rowptr, n, e);
    k_scanwrite<<<nchunks, 256, 0, stream>>>(deg, csum, rowptr, dinv, n);
    k_fill<<<(e + 255) / 256, 256, 0, stream>>>(src, dst, rowptr, cursor, esrc, e);

    // ---- layer 1 ----
    k_gemm1<<<(n + 63) / 64, 256, 0, stream>>>(x, W1, dinv, P1, n);
    k_agg1<<<(n + 3) / 4, 256, 0, stream>>>(rowptr, esrc, (const float4*)P1, dinv, b1,
                                            (float4*)h, n);

    // ---- layer 2 (P2 reuses P1 buffer) ----
    k_gemm2<<<(n + 63) / 64, 256, 0, stream>>>(h, W2, dinv, P1, n);
    k_agg2<<<(n + 3) / 4, 256, 0, stream>>>(rowptr, esrc, (const float4*)P1, dinv, b2,
                                            (float4*)out, n);
}